// Round 4
// baseline (173.753 us; speedup 1.0000x reference)
//
#include <hip/hip_runtime.h>
#include <hip/hip_bf16.h>

typedef __attribute__((ext_vector_type(4))) float f32x4;
typedef __attribute__((ext_vector_type(8))) short bf16x8;

#define S_EPI 68  // epilogue LDS stride (dwords): quad offset 4*68=272 = 16 mod 32 -> 2-way (free)

__device__ __forceinline__ short f2bf(float f) {
  __hip_bfloat16 h = __float2bfloat16(f);
  return __builtin_bit_cast(short, h);
}

// ---------------------------------------------------------------------------
// GEMM view: C[8192 x 512] = A[8192 x 1024] * B[1024 x 512], k = j*4 + kc,
// kc -> x component {0,1,2,4}.  512 cols = [c0 of i=0..255 | c4 of i=0..255].
// Column group cg (32 groups of 16): cg<16 -> c0 points cg*16.., cg>=16 -> c4.
//
// Bp (d_ws, 1 MB) holds B in exact per-lane MFMA-fragment order:
//   Bp[it][cg][lane][kk=0..7]  (16 B per lane)
// so the main kernel fetches one B frag with a single fully-coalesced
// global_load_dwordx4 (1 KB contiguous per wave) -- no LDS, no barrier.
// Frag layout (16x16x32): lane l=(q=l>>4, ln=l&15) holds B[k=q*8+kk][col=ln].
// ---------------------------------------------------------------------------
__global__ __launch_bounds__(256) void ga_prep_B(const float* __restrict__ W,
                                                 short* __restrict__ Bp) {
  const int gid = blockIdx.x * 256 + threadIdx.x;  // 65536 = 32 it * 32 cg * 64 lane
  const int l  = gid & 63;
  const int cg = (gid >> 6) & 31;
  const int it = gid >> 11;
  const int ln = l & 15, q = l >> 4;
  const int hc = cg >> 4;                 // 0 -> c0 row, 1 -> c4 row
  const int i  = (cg & 15) * 16 + ln;
  const int j0 = it * 8 + q * 2;          // kk 0..3 -> j0, kk 4..7 -> j0+1
  const float4* W4 = (const float4*)W;

  bf16x8 o;
#pragma unroll
  for (int jj = 0; jj < 2; ++jj) {
    const float4 wv = W4[((j0 + jj) * 256 + i) * 2];  // W[j][i][0..3]
    if (!hc) {
      o[jj * 4 + 0] = f2bf(wv.x); o[jj * 4 + 1] = f2bf(wv.y);
      o[jj * 4 + 2] = f2bf(wv.z); o[jj * 4 + 3] = 0;
    } else {
      o[jj * 4 + 0] = 0;          o[jj * 4 + 1] = f2bf(wv.z);
      o[jj * 4 + 2] = f2bf(-wv.y); o[jj * 4 + 3] = f2bf(wv.x);
    }
  }
  *(bf16x8*)&Bp[(size_t)gid * 8] = o;
}

// ---------------------------------------------------------------------------
// Main: 512 blocks x 256 threads (4 waves). NO LDS / NO BARRIER in main loop.
// Block: rows bm*32..+32, points ph*128..+128 (both c0 & c4 halves).
// Wave w: same 32 rows x 32 points (pg = ph*4+w). Per K-tile (K=32):
//   A: per-lane global loads of x (rows = ln, j = q*2+{0,1}) + in-reg cvt.
//      All 4 waves read identical A addresses -> L1 reuse.
//   B: 4 coalesced frag loads from Bp (L2-hot).
//   8 MFMA. Pipeline depth 3 (loads for it+3 issue at it) -> fine-grained
//   vmcnt cover ~3 tile-times; no vmcnt(0) drains anywhere in the loop.
// Epilogue: per-wave LDS transpose (one __syncthreads total), then
// full-multivector writes: lane 2p+h covers 16 B half h of point p ->
// 1 KB contiguous per store instruction (keeps WRITE_SIZE at the 64 MB ideal).
// ---------------------------------------------------------------------------
__global__ __launch_bounds__(256, 2) void ga_mv_main(
    const float* __restrict__ x, const short* __restrict__ Bp,
    const float* __restrict__ bias, float* __restrict__ y) {
  __shared__ float c_lds[4][32 * S_EPI];  // 34,816 B

  const int t = threadIdx.x;
  const int id = blockIdx.x;
  const int g = id & 7;                // XCD slot: the two ph-blocks of one bm
  const int ph = (id >> 3) & 1;        // share an XCD -> x L2 reuse
  const int bm = (id >> 4) * 8 + g;    // 0..255 row tile
  const int lane = t & 63, w = t >> 6;
  const int ln = lane & 15, q = lane >> 4;
  const int pg = ph * 4 + w;           // 32-point group (0..7)

  const float* xb0 = x + (size_t)(bm * 32 + ln) * 2048;  // rowgrp0 row, comp 0
  const int cg0 = pg * 2, cg2 = 16 + pg * 2;

  float4 xa[3][4];   // [buf][rowgrp*2 + jj]
  float  xs[3][4];
  bf16x8 bfr[3][4];  // [buf][n]

#define LOAD_A(buf, itv)                                                 \
  {                                                                      \
    const float* pA = xb0 + (itv) * 64 + q * 16;                         \
    xa[buf][0] = *(const float4*)pA;       xs[buf][0] = pA[4];           \
    xa[buf][1] = *(const float4*)(pA + 8); xs[buf][1] = pA[12];          \
    const float* pB = pA + 16 * 2048;                                    \
    xa[buf][2] = *(const float4*)pB;       xs[buf][2] = pB[4];           \
    xa[buf][3] = *(const float4*)(pB + 8); xs[buf][3] = pB[12];          \
  }

#define LOAD_B(buf, itv)                                                 \
  {                                                                      \
    const short* base = Bp + (size_t)(itv) * 32 * 64 * 8 + lane * 8;     \
    bfr[buf][0] = *(const bf16x8*)(base + (cg0    ) * 64 * 8);           \
    bfr[buf][1] = *(const bf16x8*)(base + (cg0 + 1) * 64 * 8);           \
    bfr[buf][2] = *(const bf16x8*)(base + (cg2    ) * 64 * 8);           \
    bfr[buf][3] = *(const bf16x8*)(base + (cg2 + 1) * 64 * 8);           \
  }

  LOAD_A(0, 0) LOAD_B(0, 0)
  LOAD_A(1, 1) LOAD_B(1, 1)
  LOAD_A(2, 2) LOAD_B(2, 2)

  f32x4 acc[8] = {};

#pragma unroll
  for (int it = 0; it < 32; ++it) {
    const int buf = it % 3;
    bf16x8 a0, a1;
    a0[0] = f2bf(xa[buf][0].x); a0[1] = f2bf(xa[buf][0].y);
    a0[2] = f2bf(xa[buf][0].z); a0[3] = f2bf(xs[buf][0]);
    a0[4] = f2bf(xa[buf][1].x); a0[5] = f2bf(xa[buf][1].y);
    a0[6] = f2bf(xa[buf][1].z); a0[7] = f2bf(xs[buf][1]);
    a1[0] = f2bf(xa[buf][2].x); a1[1] = f2bf(xa[buf][2].y);
    a1[2] = f2bf(xa[buf][2].z); a1[3] = f2bf(xs[buf][2]);
    a1[4] = f2bf(xa[buf][3].x); a1[5] = f2bf(xa[buf][3].y);
    a1[6] = f2bf(xa[buf][3].z); a1[7] = f2bf(xs[buf][3]);
#pragma unroll
    for (int n = 0; n < 4; ++n) {
      acc[n]     = __builtin_amdgcn_mfma_f32_16x16x32_bf16(a0, bfr[buf][n], acc[n],     0, 0, 0);
      acc[4 + n] = __builtin_amdgcn_mfma_f32_16x16x32_bf16(a1, bfr[buf][n], acc[4 + n], 0, 0, 0);
    }
    if (it + 3 < 32) {
      LOAD_A(buf, it + 3)
      LOAD_B(buf, it + 3)
    }
  }

  // ---- epilogue ----
  // C/D layout: col = ln, row = q*4 + r. Frag n covers cols n*16+ln of the
  // wave's 64-col space: cols 0..31 = c0 of points pg*32..+32, 32..63 = c4.
  float* cw = &c_lds[w][0];
#pragma unroll
  for (int m = 0; m < 2; ++m)
#pragma unroll
    for (int n = 0; n < 4; ++n)
#pragma unroll
      for (int r = 0; r < 4; ++r)
        cw[(m * 16 + q * 4 + r) * S_EPI + n * 16 + ln] = acc[m * 4 + n][r];
  __syncthreads();  // the only barrier in the kernel (also orders LDS ops)

  const int p = lane >> 1, h = lane & 1;  // lane 2p+h -> point p, 16B half h
  const float4 bv = ((const float4*)bias)[(pg * 32 + p) * 2 + h];
  float4* y4 = (float4*)y;
#pragma unroll
  for (int b = 0; b < 32; ++b) {
    float4 o = bv;
    o.x += cw[b * S_EPI + h * 32 + p];  // +c0 into comp0 / +c4 into comp4
    y4[((size_t)(bm * 32 + b) * 256 + pg * 32 + p) * 2 + h] = o;
  }
}

extern "C" void kernel_launch(void* const* d_in, const int* in_sizes, int n_in,
                              void* d_out, int out_size, void* d_ws, size_t ws_size,
                              hipStream_t stream) {
  const float* x = (const float*)d_in[0];
  const float* W = (const float*)d_in[1];
  const float* bias = (const float*)d_in[2];
  float* y = (float*)d_out;
  short* Bp = (short*)d_ws;  // 32*32*64*16 = 1,048,576 B

  ga_prep_B<<<dim3(256), dim3(256), 0, stream>>>(W, Bp);
  ga_mv_main<<<dim3(512), dim3(256), 0, stream>>>(x, Bp, bias, y);
}

// Round 5
// 133.117 us; speedup vs baseline: 1.3053x; 1.3053x over previous
//
#include <hip/hip_runtime.h>
#include <hip/hip_bf16.h>

typedef __attribute__((ext_vector_type(4))) float f32x4;
typedef __attribute__((ext_vector_type(8))) short bf16x8;
typedef __attribute__((ext_vector_type(4))) short short4v;

#define AROW 264  // shorts per A-LDS row: 64 j * 4 + 8 pad = 528 B (16B-aligned, odd quad-stride -> BW-floor b128 reads)
#define CS 516    // dwords per epilogue c row (512 + 4 pad -> 2-way max, free)

__device__ __forceinline__ short f2bf(float f) {
  __hip_bfloat16 h = __float2bfloat16(f);
  return __builtin_bit_cast(short, h);
}

// ---------------------------------------------------------------------------
// GEMM view: C[8192 x 512] = A[8192 x 1024] * B[1024 x 512], k = j*4 + kc,
// kc -> x component {0,1,2,4}.  512 cols = [c0 of i=0..255 | c4 of i=0..255].
// Bp (d_ws, 1 MB): per-lane MFMA B-fragment order Bp[it][cg][lane][8 shorts],
// cg = col/16. One frag load = 1 KB contiguous per wave (L2-hot).
// ---------------------------------------------------------------------------
__global__ __launch_bounds__(256) void ga_prep_B(const float* __restrict__ W,
                                                 short* __restrict__ Bp) {
  const int gid = blockIdx.x * 256 + threadIdx.x;  // 65536 = 32 it * 32 cg * 64 lane
  const int l  = gid & 63;
  const int cg = (gid >> 6) & 31;
  const int it = gid >> 11;
  const int ln = l & 15, q = l >> 4;
  const int hc = cg >> 4;                 // 0 -> c0 row, 1 -> c4 row
  const int i  = (cg & 15) * 16 + ln;
  const int j0 = it * 8 + q * 2;
  const float4* W4 = (const float4*)W;

  bf16x8 o;
#pragma unroll
  for (int jj = 0; jj < 2; ++jj) {
    const float4 wv = W4[((j0 + jj) * 256 + i) * 2];  // W[j][i][0..3]
    if (!hc) {
      o[jj * 4 + 0] = f2bf(wv.x); o[jj * 4 + 1] = f2bf(wv.y);
      o[jj * 4 + 2] = f2bf(wv.z); o[jj * 4 + 3] = 0;
    } else {
      o[jj * 4 + 0] = 0;           o[jj * 4 + 1] = f2bf(wv.z);
      o[jj * 4 + 2] = f2bf(-wv.y); o[jj * 4 + 3] = f2bf(wv.x);
    }
  }
  *(bf16x8*)&Bp[(size_t)gid * 8] = o;
}

// ---------------------------------------------------------------------------
// Main: 512 blocks (16 rows x ALL 512 cols) x 512 threads (8 waves) ->
// 2 blocks/CU, 16 waves/CU. K in 4 quarters of 256 (64 j). Per quarter:
// bulk-coalesced x slab -> regs (4 float4/thread, every instr contiguous) ->
// shuffle comp4 -> bf16 -> A_lds (double-buffered). K-loop: A from LDS,
// B frags from L2-hot Bp (depth-2 reg pipeline), 4 MFMA/wave/iter, NO global
// x access, ONE barrier per quarter. Epilogue: full-multivector writes.
// ---------------------------------------------------------------------------
__global__ __launch_bounds__(512, 2) void ga_mv_main(
    const float* __restrict__ x, const short* __restrict__ Bp,
    const float* __restrict__ bias, float* __restrict__ y) {
  __shared__ __align__(16) char smem[33088];
  short* Abuf[2] = {(short*)smem, (short*)(smem + 16 * AROW * 2)};
  float* c_lds = (float*)smem;  // epilogue alias (A dead by then): 16*516*4 = 33024

  const int t = threadIdx.x;
  const int bm = blockIdx.x;         // 512 blocks x 16 rows
  const int lane = t & 63, w = t >> 6;
  const int ln = lane & 15, qq = lane >> 4;
  const int R0 = bm * 16;

  // staging map: thread t, i=0..3 -> row = (t>>7)+4i, float4-col c4i = t&127
  //   c4i = j_local*2 + h  (h: 0 -> comps 0-3, 1 -> comps 4-7)
  const int ci = t & 127, rb = t >> 7;
  const int jl = ci >> 1, h2 = ci & 1;
  const float4* x4 = (const float4*)x;
  float4 fr[4];

#define LOADX(qtr)                                                           \
  {                                                                          \
    _Pragma("unroll")                                                        \
    for (int i = 0; i < 4; ++i)                                              \
      fr[i] = x4[(size_t)(R0 + rb + 4 * i) * 512 + (qtr) * 128 + ci];        \
  }

#define PROC(dst)                                                            \
  {                                                                          \
    _Pragma("unroll")                                                        \
    for (int i = 0; i < 4; ++i) {                                            \
      const float c4 = __shfl_xor(fr[i].x, 1, 64);                           \
      if (!h2) {                                                             \
        short4v a;                                                           \
        a[0] = f2bf(fr[i].x); a[1] = f2bf(fr[i].y);                          \
        a[2] = f2bf(fr[i].z); a[3] = f2bf(c4);                               \
        *(short4v*)&(dst)[(rb + 4 * i) * AROW + jl * 4] = a;                 \
      }                                                                      \
    }                                                                        \
  }

  // B frag pipeline (depth 2). Wave w owns cgs w*4 .. w*4+3.
  const size_t bbase = (size_t)w * 4 * 512 + lane * 8;
  bf16x8 Bf[2][4];
#define LB(itv, b)                                                           \
  {                                                                          \
    const short* p = Bp + (size_t)(itv) * 32 * 512 + bbase;                  \
    Bf[b][0] = *(const bf16x8*)(p);                                          \
    Bf[b][1] = *(const bf16x8*)(p + 512);                                    \
    Bf[b][2] = *(const bf16x8*)(p + 1024);                                   \
    Bf[b][3] = *(const bf16x8*)(p + 1536);                                   \
  }

  // ---- prologue ----
  LOADX(0);
  PROC(Abuf[0]);
  __syncthreads();
  LB(0, 0);
  LB(1, 1);
  LOADX(1);  // in flight across quarter 0

  f32x4 acc[4] = {};

#pragma unroll
  for (int q = 0; q < 4; ++q) {
    const short* Ac = Abuf[q & 1];
#pragma unroll
    for (int tau = 0; tau < 8; ++tau) {
      const int it = q * 8 + tau;
      if (tau == 4 && q < 3) {
        PROC(Abuf[(q + 1) & 1]);       // waits the LOADX issued last quarter
        if (q < 2) LOADX(q + 2);       // refill fr for next quarter's PROC
      }
      const bf16x8 af = *(const bf16x8*)&Ac[ln * AROW + (tau * 8 + qq * 2) * 4];
#pragma unroll
      for (int n = 0; n < 4; ++n)
        acc[n] = __builtin_amdgcn_mfma_f32_16x16x32_bf16(af, Bf[it & 1][n],
                                                         acc[n], 0, 0, 0);
      if (it + 2 < 32) LB(it + 2, it & 1);
    }
    __syncthreads();  // one barrier per quarter: A-buf swap guard
  }

  // ---- epilogue: acc -> c_lds (cols = w*64+n*16+ln), full-mv y writes ----
  // C/D layout: col = ln, row = qq*4 + r
#pragma unroll
  for (int n = 0; n < 4; ++n)
#pragma unroll
    for (int r = 0; r < 4; ++r)
      c_lds[(qq * 4 + r) * CS + w * 64 + n * 16 + ln] = acc[n][r];
  __syncthreads();

  const int h = t & 1, p = t >> 1;  // point p, 16B half h -> contiguous stores
  const float4 bv = ((const float4*)bias)[p * 2 + h];
  float4* y4 = (float4*)y;
#pragma unroll
  for (int r = 0; r < 16; ++r) {
    float4 o = bv;
    o.x += c_lds[r * CS + h * 256 + p];  // +c0 into comp0 / +c4 into comp4
    y4[((size_t)(R0 + r) * 256 + p) * 2 + h] = o;
  }
}

extern "C" void kernel_launch(void* const* d_in, const int* in_sizes, int n_in,
                              void* d_out, int out_size, void* d_ws, size_t ws_size,
                              hipStream_t stream) {
  const float* x = (const float*)d_in[0];
  const float* W = (const float*)d_in[1];
  const float* bias = (const float*)d_in[2];
  float* y = (float*)d_out;
  short* Bp = (short*)d_ws;  // 32*32*64*16 = 1,048,576 B

  ga_prep_B<<<dim3(256), dim3(256), 0, stream>>>(W, Bp);
  ga_mv_main<<<dim3(512), dim3(512), 0, stream>>>(x, Bp, bias, y);
}